// Round 10
// baseline (1106.377 us; speedup 1.0000x reference)
//
#include <hip/hip_runtime.h>
#include <math.h>

#define NPTS 256
#define NSRC 1024
#define NITER 100
#define KCONV 577.0780163555854f         // log2(e)/eps
#define INV_KC 0.0017328679513998632f    // eps*ln2
#define EPS_LBC (-0.013862943611198906f) // eps*ln(1/256)
#define EPSQ 0.0025f
#define NEG_BIG (-1e30f)
#define TAGM 15u
#define S_IMG 4

#define EXP2F(x) __builtin_amdgcn_exp2f(x)
#define LOG2F(x) __builtin_amdgcn_logf(x)
#define F4E(v,e) ((e)==0?(v).x:(e)==1?(v).y:(e)==2?(v).z:(v).w)

// exchange per image (4096 words): F parity p at +p*1024; G parity p at +2048+p*256
#define IMG_EX(i) ((i) * 4096)
#define WS_PART_W 32768

__device__ __forceinline__ void stp(unsigned int* p, float v, unsigned int tag) {
  __hip_atomic_store(p, (__float_as_uint(v) & ~TAGM) | tag,
                     __ATOMIC_RELAXED, __HIP_MEMORY_SCOPE_AGENT);
}
__device__ __forceinline__ unsigned int ldp(const unsigned int* p) {
  return __hip_atomic_load(p, __ATOMIC_RELAXED, __HIP_MEMORY_SCOPE_AGENT);
}
__device__ __forceinline__ float4 poll4(const unsigned int* p, unsigned int tg) {
  unsigned int u0, u1, u2, u3;
  for (;;) {
    u0 = ldp(p); u1 = ldp(p + 1); u2 = ldp(p + 2); u3 = ldp(p + 3);
    if (((((u0 & TAGM) ^ tg) | ((u1 & TAGM) ^ tg)) |
         (((u2 & TAGM) ^ tg) | ((u3 & TAGM) ^ tg))) == 0u) break;
    __builtin_amdgcn_s_sleep(1);
  }
  return make_float4(__uint_as_float(u0 & ~TAGM), __uint_as_float(u1 & ~TAGM),
                     __uint_as_float(u2 & ~TAGM), __uint_as_float(u3 & ~TAGM));
}

__global__ __launch_bounds__(1024)
void ot_sinkhorn(const float* __restrict__ dens_all,
                 const float* __restrict__ pts_all,
                 unsigned int* __restrict__ wsu)
{
  // ---- ab (4 image slots) ----
  __shared__ __align__(16) float F_L[S_IMG][32 * 36];
  __shared__ __align__(16) float G_L[S_IMG][16 * 20];
  __shared__ __align__(16) float pxP[S_IMG][16 * 20], pyP[S_IMG][16 * 20];
  __shared__ __align__(16) float a_own[S_IMG][64], ela_own[S_IMG][64];
  // ---- bb ----
  __shared__ __align__(16) float pxL[NPTS], pyL[NPTS], FbS[NPTS], GbS[NPTS];
  // ---- aa ----
  __shared__ __align__(16) float FaL[NSRC], TaL[32 * 33], PM[16 * 33], CM[32];
  __shared__ float red[16];

  const int tid = threadIdx.x;
  const int bid = blockIdx.x;
  float* partials = (float*)(wsu + WS_PART_W);
  float acc = 0.0f;

  if (bid < 32) {
    // ============ ot_ab : 2 teams x 16 blocks x 4 images, 2 hidden hops/iter ============
    const int team = bid >> 4, sub = bid & 15;

    #pragma unroll
    for (int s = 0; s < S_IMG; ++s) {
      const int img = team * S_IMG + s;
      const float* dens = dens_all + img * NSRC;
      const float* pts = pts_all + img * (NPTS * 2);
      if (tid < NPTS) {
        pxP[s][(tid >> 4) * 20 + (tid & 15)] = pts[2 * tid];
        pyP[s][(tid >> 4) * 20 + (tid & 15)] = pts[2 * tid + 1];
      }
      { float a = dens[tid];
        F_L[s][(tid >> 5) * 36 + (tid & 31)] = (a > 0.0f) ? EPSQ * __logf(a) : NEG_BIG; }
      if (tid < 64) {
        float a = dens[sub * 64 + tid];
        a_own[s][tid] = a;
        ela_own[s][tid] = (a > 0.0f) ? EPSQ * __logf(a) : NEG_BIG;
      }
    }
    __syncthreads();

    const int w = tid >> 6, lane = tid & 63;
    const int r = lane & 31, h = lane >> 5;
    const int jg = sub * 16 + w;                  // g-half: one wave per target
    const float ry = (float)(r * 8 + 4);
    const float xb = (float)(h * 128 + 4);
    const int cl = tid >> 4, ch = tid & 15;       // f-half: 16 lanes per cell
    const int cc = sub * 64 + cl;
    const float cx = (float)((cc & 31) * 8 + 4);
    const float cy = (float)((cc >> 5) * 8 + 4);

    float tt[16];
    auto ghalf = [&](int s) -> float {
      const float4* FL4 = (const float4*)F_L[s];
      const float pxj = pxP[s][(jg >> 4) * 20 + (jg & 15)];
      const float pyj = pyP[s][(jg >> 4) * 20 + (jg & 15)];
      const float dy = ry - pyj, dy2 = dy * dy;
      const float px0 = xb - pxj;
      float m = -INFINITY;
      #pragma unroll
      for (int k = 0; k < 4; ++k) {
        float4 Fv = FL4[r * 9 + h * 4 + k];
        #pragma unroll
        for (int e = 0; e < 4; ++e) {
          float dx = px0 + (float)(k * 32 + e * 8);
          float v = fmaf(fmaf(dx, dx, dy2), -0.5f, F4E(Fv, e));
          tt[k * 4 + e] = v; m = fmaxf(m, v);
        }
      }
      #pragma unroll
      for (int o = 1; o < 64; o <<= 1) m = fmaxf(m, __shfl_xor(m, o, 64));
      const float mk = m * KCONV;
      float ss = 0.0f;
      #pragma unroll
      for (int i = 0; i < 16; ++i) ss += EXP2F(fmaf(tt[i], KCONV, -mk));
      #pragma unroll
      for (int o = 1; o < 64; o <<= 1) ss += __shfl_xor(ss, o, 64);
      return -(m + LOG2F(ss) * INV_KC);
    };
    auto fhalf = [&](int s) -> float {
      const float4* GL4 = (const float4*)G_L[s];
      const float4* px4 = (const float4*)pxP[s];
      const float4* py4 = (const float4*)pyP[s];
      float m = -INFINITY;
      #pragma unroll
      for (int k = 0; k < 4; ++k) {
        float4 pxv = px4[ch * 5 + k], pyv = py4[ch * 5 + k], Gv = GL4[ch * 5 + k];
        #pragma unroll
        for (int e = 0; e < 4; ++e) {
          float dx = F4E(pxv, e) - cx, dq = F4E(pyv, e) - cy;
          float v = fmaf(fmaf(dq, dq, dx * dx), -0.5f, F4E(Gv, e));
          tt[k * 4 + e] = v; m = fmaxf(m, v);
        }
      }
      #pragma unroll
      for (int o = 1; o < 16; o <<= 1) m = fmaxf(m, __shfl_xor(m, o, 64));
      const float mk = m * KCONV;
      float ss = 0.0f;
      #pragma unroll
      for (int i = 0; i < 16; ++i) ss += EXP2F(fmaf(tt[i], KCONV, -mk));
      #pragma unroll
      for (int o = 1; o < 16; o <<= 1) ss += __shfl_xor(ss, o, 64);
      return -(m + LOG2F(ss) * INV_KC);
    };

    for (int k = 1; k <= NITER; ++k) {
      const unsigned tg = (unsigned)k & TAGM;
      const unsigned tgp = (unsigned)(k - 1) & TAGM;
      // ---- 4 G-phases: poll F(s,k-1) -> ghalf -> store G(s,k) ----
      #pragma unroll
      for (int s = 0; s < S_IMG; ++s) {
        unsigned int* EXF = wsu + IMG_EX(team * S_IMG + s);
        if (k > 1 && tid < 256) {
          float4 v = poll4(EXF + ((k - 1) & 1) * 1024 + tid * 4, tgp);
          int c = tid * 4;
          *(float4*)(F_L[s] + (c >> 5) * 36 + (c & 31)) = v;
        }
        __syncthreads();
        float g = ghalf(s);
        if (lane == 0) stp(EXF + 2048 + (k & 1) * 256 + jg, g + EPS_LBC, tg);
      }
      // ---- 4 F-phases: poll G(s,k) -> fhalf -> store F(s,k) ----
      #pragma unroll
      for (int s = 0; s < S_IMG; ++s) {
        unsigned int* EXF = wsu + IMG_EX(team * S_IMG + s);
        if (tid < 64) {
          float4 v = poll4(EXF + 2048 + (k & 1) * 256 + tid * 4, tg);
          int j = tid * 4;
          *(float4*)(G_L[s] + (j >> 4) * 20 + (j & 15)) = v;
        }
        __syncthreads();
        float f = fhalf(s);
        if (ch == 0) {
          stp(EXF + (k & 1) * 1024 + cc, f + ela_own[s][cl], tg);
          if (k == NITER) acc += a_own[s][cl] * f;       // sum a * f^100
        }
      }
    }
    // ---- tail: g^101 = U(f^100) ----
    {
      const unsigned tgN = (unsigned)NITER & TAGM;
      #pragma unroll
      for (int s = 0; s < S_IMG; ++s) {
        unsigned int* EXF = wsu + IMG_EX(team * S_IMG + s);
        if (tid < 256) {
          float4 v = poll4(EXF + (NITER & 1) * 1024 + tid * 4, tgN);
          int c = tid * 4;
          *(float4*)(F_L[s] + (c >> 5) * 36 + (c & 31)) = v;
        }
        __syncthreads();
        float g = ghalf(s);
        if (lane == 0) acc += g * (1.0f / 256.0f);
      }
    }
  } else if (bid < 40) {
    // ============ ot_bb : one block, in-LDS ============
    const int img = bid - 32;
    const float* pts = pts_all + img * (NPTS * 2);
    if (tid < NPTS) {
      pxL[tid] = pts[2 * tid];
      pyL[tid] = pts[2 * tid + 1];
      FbS[tid] = EPS_LBC;                           // f = 0
    }
    __syncthreads();

    const int cl = tid >> 4, ch = tid & 15;
    float4 px4[4], py4[4];
    #pragma unroll
    for (int k = 0; k < 4; ++k) {
      px4[k] = *(const float4*)(pxL + ch * 16 + k * 4);
      py4[k] = *(const float4*)(pyL + ch * 16 + k * 4);
    }
    const float4* Fb4 = (const float4*)FbS;
    const float4* Gb4 = (const float4*)GbS;

    float tt[16];
    for (int it = 0;; ++it) {
      float4 A4[4];
      #pragma unroll
      for (int k = 0; k < 4; ++k) A4[k] = Fb4[ch * 4 + k];
      #pragma unroll 1
      for (int p = 0; p < 4; ++p) {
        const int tj = p * 64 + cl;
        const float qx = pxL[tj], qy = pyL[tj];
        float m = -INFINITY;
        #pragma unroll
        for (int k = 0; k < 4; ++k) {
          #pragma unroll
          for (int e = 0; e < 4; ++e) {
            float dx = F4E(px4[k], e) - qx;
            float dyq = F4E(py4[k], e) - qy;
            float u = fmaf(dyq, dyq, dx * dx);
            float v = fmaf(u, -0.5f, F4E(A4[k], e));
            tt[k * 4 + e] = v; m = fmaxf(m, v);
          }
        }
        #pragma unroll
        for (int o = 1; o < 16; o <<= 1) m = fmaxf(m, __shfl_xor(m, o, 64));
        const float mk = m * KCONV;
        float s = 0.0f;
        #pragma unroll
        for (int i = 0; i < 16; ++i) s += EXP2F(fmaf(tt[i], KCONV, -mk));
        #pragma unroll
        for (int o = 1; o < 16; o <<= 1) s += __shfl_xor(s, o, 64);
        const float g = -(m + LOG2F(s) * INV_KC);
        if (it == NITER) { if (ch == 0) acc += g * (1.0f / 256.0f); }
        else if (ch == 0) GbS[tj] = g + EPS_LBC;
      }
      if (it == NITER) break;
      __syncthreads();

      float4 B4[4];
      #pragma unroll
      for (int k = 0; k < 4; ++k) B4[k] = Gb4[ch * 4 + k];
      #pragma unroll 1
      for (int p = 0; p < 4; ++p) {
        const int tj = p * 64 + cl;
        const float qx = pxL[tj], qy = pyL[tj];
        float m = -INFINITY;
        #pragma unroll
        for (int k = 0; k < 4; ++k) {
          #pragma unroll
          for (int e = 0; e < 4; ++e) {
            float dx = F4E(px4[k], e) - qx;
            float dyq = F4E(py4[k], e) - qy;
            float u = fmaf(dyq, dyq, dx * dx);
            float v = fmaf(u, -0.5f, F4E(B4[k], e));
            tt[k * 4 + e] = v; m = fmaxf(m, v);
          }
        }
        #pragma unroll
        for (int o = 1; o < 16; o <<= 1) m = fmaxf(m, __shfl_xor(m, o, 64));
        const float mk = m * KCONV;
        float s = 0.0f;
        #pragma unroll
        for (int i = 0; i < 16; ++i) s += EXP2F(fmaf(tt[i], KCONV, -mk));
        #pragma unroll
        for (int o = 1; o < 16; o <<= 1) s += __shfl_xor(s, o, 64);
        if (ch == 0) {
          const float f = -(m + LOG2F(s) * INV_KC);
          FbS[tj] = f + EPS_LBC;
          if (it == NITER - 1) acc += f * (1.0f / 256.0f);
        }
      }
      __syncthreads();
    }
  } else {
    // ============ ot_aa : one block, separable LSE + verified diagonal collapse ============
    const int img = bid - 40;
    const float* dens = dens_all + img * NSRC;
    const float d_np = dens[tid];
    const float a_np = d_np;
    const float epsla_np = (d_np > 0.0f) ? EPSQ * __logf(d_np) : NEG_BIG;
    float myF = epsla_np;
    FaL[tid] = myF;
    __syncthreads();

    const int w = tid >> 6, lane = tid & 63;
    const int q1 = tid & 31, r1 = tid >> 5;
    const int q2 = q1, r2 = r1;

    auto aa_half = [&]() -> float {
      float cp = fmaxf(myF, __shfl_xor(myF, 32, 64));
      if (lane < 32) PM[w * 33 + lane] = cp;
      __syncthreads();
      if (tid < 32) {
        float cm = -INFINITY;
        #pragma unroll
        for (int w2 = 0; w2 < 16; ++w2) cm = fmaxf(cm, PM[w2 * 33 + tid]);
        CM[tid] = cm;
      }
      __syncthreads();
      const float fmx = CM[q1];
      float Tv;
      if (__all(fmx - 32.0f <= myF - 0.25f)) {
        Tv = myF;
      } else {
        float tv[32]; float m = -INFINITY; float d = (float)(-r1);
        #pragma unroll
        for (int rr = 0; rr < 32; ++rr) {
          float v = fmaf(d * d, -32.0f, FaL[rr * 32 + q1]);
          tv[rr] = v; m = fmaxf(m, v); d += 1.0f;
        }
        const float mk = m * KCONV; float s = 0.0f;
        #pragma unroll
        for (int rr = 0; rr < 32; ++rr) s += EXP2F(fmaf(tv[rr], KCONV, -mk));
        Tv = m + LOG2F(s) * INV_KC;
      }
      TaL[q1 * 33 + r1] = Tv;
      __syncthreads();
      float tmx = Tv;
      #pragma unroll
      for (int o = 1; o < 32; o <<= 1) tmx = fmaxf(tmx, __shfl_xor(tmx, o, 64));
      float outv;
      if (__all(tmx - 32.0f <= Tv - 0.25f)) {
        outv = Tv;
      } else {
        float tv[32]; float m = -INFINITY; float d = (float)(-q2);
        #pragma unroll
        for (int qi = 0; qi < 32; ++qi) {
          float v = fmaf(d * d, -32.0f, TaL[qi * 33 + r2]);
          tv[qi] = v; m = fmaxf(m, v); d += 1.0f;
        }
        const float mk = m * KCONV; float s = 0.0f;
        #pragma unroll
        for (int qi = 0; qi < 32; ++qi) s += EXP2F(fmaf(tv[qi], KCONV, -mk));
        outv = m + LOG2F(s) * INV_KC;
      }
      __syncthreads();
      return -outv;
    };

    for (int it = 0;; ++it) {
      float gpot = aa_half();
      if (it == NITER) { acc += a_np * gpot; break; }
      myF = gpot + epsla_np; FaL[tid] = myF;
      __syncthreads();
      float fpot = aa_half();
      if (it == NITER - 1) acc += a_np * fpot;
      myF = fpot + epsla_np; FaL[tid] = myF;
      __syncthreads();
    }
  }

  // ---- block reduction + per-block partial ----
  {
    #pragma unroll
    for (int o = 32; o; o >>= 1) acc += __shfl_xor(acc, o, 64);
    __syncthreads();
    if ((tid & 63) == 0) red[tid >> 6] = acc;
    __syncthreads();
    if (tid == 0) {
      float tsum = 0.0f;
      #pragma unroll
      for (int k = 0; k < 16; ++k) tsum += red[k];
      partials[bid] = tsum;
    }
  }
}

__global__ void ot_finalize(const float* __restrict__ partials, float* __restrict__ out) {
  const int tid = threadIdx.x;
  float v = 0.0f;
  if (tid < 48) v = ((tid < 32) ? 1.0f : -0.5f) * partials[tid];
  #pragma unroll
  for (int o = 32; o; o >>= 1) v += __shfl_xor(v, o, 64);
  if (tid == 0) out[0] = v;
}

extern "C" void kernel_launch(void* const* d_in, const int* in_sizes, int n_in,
                              void* d_out, int out_size, void* d_ws, size_t ws_size,
                              hipStream_t stream) {
  const float* dens = (const float*)d_in[0];   // (8,1,32,32) f32
  const float* pts  = (const float*)d_in[1];   // (8,256,2)   f32
  unsigned int* wsu = (unsigned int*)d_ws;
  ot_sinkhorn<<<dim3(48), dim3(1024), 0, stream>>>(dens, pts, wsu);
  ot_finalize<<<dim3(1), dim3(64), 0, stream>>>((const float*)(wsu + WS_PART_W), (float*)d_out);
}

// Round 11
// 453.855 us; speedup vs baseline: 2.4377x; 2.4377x over previous
//
#include <hip/hip_runtime.h>
#include <math.h>

#define NPTS 256
#define NSRC 1024
#define NITER 100
#define KCONV 577.0780163555854f         // log2(e)/eps
#define INV_KC 0.0017328679513998632f    // eps*ln2
#define EPS_LBC (-0.013862943611198906f) // eps*ln(1/256)
#define EPSQ 0.0025f
#define NEG_BIG (-1e30f)
#define TAGM 15u

#define EXP2F(x) __builtin_amdgcn_exp2f(x)
#define LOG2F(x) __builtin_amdgcn_logf(x)
#define F4E(v,e) ((e)==0?(v).x:(e)==1?(v).y:(e)==2?(v).z:(v).w)

// ws layout (u32 words)
#define AB_EX(i) ((i) * 8192)            // parity p at +p*4096; block b at +b*256
#define BB_EX(i) (65536 + (i) * 2048)    // parity p at +p*1024; block b at +b*256
#define WS_PART_W 131072

__device__ __forceinline__ void stp(unsigned int* p, float v, unsigned int tag) {
  __hip_atomic_store(p, (__float_as_uint(v) & ~TAGM) | tag,
                     __ATOMIC_RELAXED, __HIP_MEMORY_SCOPE_AGENT);
}
__device__ __forceinline__ unsigned int ldp(const unsigned int* p) {
  return __hip_atomic_load(p, __ATOMIC_RELAXED, __HIP_MEMORY_SCOPE_AGENT);
}

__global__ __launch_bounds__(1024)
void ot_sinkhorn(const float* __restrict__ dens_all,
                 const float* __restrict__ pts_all,
                 unsigned int* __restrict__ wsu)
{
  __shared__ __align__(16) float pxP[320], pyP[320];   // padded 16x20 point coords
  __shared__ __align__(16) float G_L[320];             // merged g staging (padded)
  __shared__ __align__(16) float F_own[64];            // block-local potentials
  __shared__ __align__(16) float a_own[64], ela_own[64];
  // ---- aa ----
  __shared__ __align__(16) float FaL[NSRC], TaL[32 * 33], PM[16 * 33], CM[32];
  __shared__ float red[16];

  const int tid = threadIdx.x;
  const int bid = blockIdx.x;
  float* partials = (float*)(wsu + WS_PART_W);
  float acc = 0.0f;

  if (bid < 128) {
    // ============ ot_ab : 8 teams x 16 blocks, single partial-exchange/iter ============
    const int img = bid >> 4, sub = bid & 15;        // block owns rows 2sub,2sub+1 (64 cells)
    const float* dens = dens_all + img * NSRC;
    const float* pts = pts_all + img * (NPTS * 2);
    unsigned int* EX = wsu + AB_EX(img);

    if (tid < NPTS) {
      pxP[(tid >> 4) * 20 + (tid & 15)] = pts[2 * tid];
      pyP[(tid >> 4) * 20 + (tid & 15)] = pts[2 * tid + 1];
    }
    if (tid < 64) {
      float a = dens[sub * 64 + tid];
      a_own[tid] = a;
      float ela = (a > 0.0f) ? EPSQ * __logf(a) : NEG_BIG;
      ela_own[tid] = ela;
      F_own[tid] = ela;                              // f = 0 (t-units)
    }
    __syncthreads();

    const int jp = tid >> 2, sl = tid & 3;           // partial/merge: 4 lanes per target
    const int cl = tid >> 4, ch = tid & 15;          // fhalf: 16 lanes per cell
    const int cc = sub * 64 + cl;
    const float cx = (float)((cc & 31) * 8 + 4);
    const float cy = (float)((cc >> 5) * 8 + 4);
    const float prow_y = (float)((sub * 2 + (sl >> 1)) * 8 + 4);  // partial lane's row
    const float px0 = (float)((sl & 1) * 128 + 4);               // partial lane's x base

    float tt[16];

    // per-target partial LSE over this block's 64 cells (each lane: 16 cells)
    auto partial_store = [&](int k) {
      const float pxj = pxP[(jp >> 4) * 20 + (jp & 15)];
      const float pyj = pyP[(jp >> 4) * 20 + (jp & 15)];
      const float dy = prow_y - pyj;
      const float base = -0.5f * dy * dy;
      const float dx0 = px0 - pxj;
      const float4* F4 = (const float4*)F_own;
      float m = -INFINITY;
      #pragma unroll
      for (int q4 = 0; q4 < 4; ++q4) {
        float4 Fv = F4[sl * 4 + q4];
        #pragma unroll
        for (int e = 0; e < 4; ++e) {
          float dx = dx0 + (float)((q4 * 4 + e) * 8);
          float v = fmaf(dx, dx * -0.5f, base + F4E(Fv, e));
          tt[q4 * 4 + e] = v; m = fmaxf(m, v);
        }
      }
      m = fmaxf(m, __shfl_xor(m, 1, 64));
      m = fmaxf(m, __shfl_xor(m, 2, 64));
      const float mk = m * KCONV;
      float ss = 0.0f;
      #pragma unroll
      for (int i = 0; i < 16; ++i) ss += EXP2F(fmaf(tt[i], KCONV, -mk));
      ss += __shfl_xor(ss, 1, 64);
      ss += __shfl_xor(ss, 2, 64);
      if (sl == 0)
        stp(EX + (k & 1) * 4096 + sub * 256 + jp, m + LOG2F(ss) * INV_KC, (unsigned)k & TAGM);
    };

    // poll 16 blocks' partials for target jp (4 per lane), merge -> g, stage G_L
    auto merge = [&](int k) -> float {
      const unsigned tg = (unsigned)k & TAGM;
      const unsigned int* base = EX + (k & 1) * 4096 + jp;
      unsigned u[4];
      for (;;) {
        unsigned bad = 0;
        #pragma unroll
        for (int i = 0; i < 4; ++i) { u[i] = ldp(base + (sl * 4 + i) * 256); bad |= (u[i] & TAGM) ^ tg; }
        if (__all(bad == 0)) break;
        __builtin_amdgcn_s_sleep(1);
      }
      float vv[4]; float m = -INFINITY;
      #pragma unroll
      for (int i = 0; i < 4; ++i) { vv[i] = __uint_as_float(u[i] & ~TAGM); m = fmaxf(m, vv[i]); }
      const float mk = m * KCONV;
      float ss = 0.0f;
      #pragma unroll
      for (int i = 0; i < 4; ++i) ss += EXP2F(fmaf(vv[i], KCONV, -mk));
      #pragma unroll
      for (int o = 1; o < 4; o <<= 1) {
        float mo = __shfl_xor(m, o, 64), so = __shfl_xor(ss, o, 64);
        float mn = fmaxf(m, mo);
        ss = ss * EXP2F((m - mn) * KCONV) + so * EXP2F((mo - mn) * KCONV);
        m = mn;
      }
      float g = -(m + LOG2F(ss) * INV_KC);
      if (sl == 0) G_L[(jp >> 4) * 20 + (jp & 15)] = g + EPS_LBC;
      return g;
    };

    // f-update for own 64 cells over all 256 targets (16 lanes/cell)
    auto fhalf = [&](int k) {
      const float4* GL4 = (const float4*)G_L;
      const float4* px4 = (const float4*)pxP;
      const float4* py4 = (const float4*)pyP;
      float m = -INFINITY;
      #pragma unroll
      for (int k4 = 0; k4 < 4; ++k4) {
        float4 pxv = px4[ch * 5 + k4], pyv = py4[ch * 5 + k4], Gv = GL4[ch * 5 + k4];
        #pragma unroll
        for (int e = 0; e < 4; ++e) {
          float dx = F4E(pxv, e) - cx, dq = F4E(pyv, e) - cy;
          float v = fmaf(fmaf(dq, dq, dx * dx), -0.5f, F4E(Gv, e));
          tt[k4 * 4 + e] = v; m = fmaxf(m, v);
        }
      }
      #pragma unroll
      for (int o = 1; o < 16; o <<= 1) m = fmaxf(m, __shfl_xor(m, o, 64));
      const float mk = m * KCONV;
      float ss = 0.0f;
      #pragma unroll
      for (int i = 0; i < 16; ++i) ss += EXP2F(fmaf(tt[i], KCONV, -mk));
      #pragma unroll
      for (int o = 1; o < 16; o <<= 1) ss += __shfl_xor(ss, o, 64);
      if (ch == 0) {
        float f = -(m + LOG2F(ss) * INV_KC);
        F_own[cl] = f + ela_own[cl];
        if (k == NITER) acc += a_own[cl] * f;        // sum a * f^100
      }
    };

    partial_store(1);
    for (int k = 1; k <= NITER; ++k) {
      merge(k);
      __syncthreads();
      fhalf(k);
      __syncthreads();
      partial_store(k + 1);
    }
    {
      float g = merge(NITER + 1);                    // g^101 = U(f^100)
      if (sub == 0 && sl == 0) acc += g * (1.0f / 256.0f);
    }
  } else if (bid < 160) {
    // ============ ot_bb : 8 teams x 4 blocks, single partial-exchange/iter ============
    const int img = (bid - 128) >> 2, sub = (bid - 128) & 3;   // block owns 64 pts
    const float* pts = pts_all + img * (NPTS * 2);
    unsigned int* EX = wsu + BB_EX(img);

    if (tid < NPTS) {
      pxP[(tid >> 4) * 20 + (tid & 15)] = pts[2 * tid];
      pyP[(tid >> 4) * 20 + (tid & 15)] = pts[2 * tid + 1];
    }
    if (tid < 64) F_own[tid] = EPS_LBC;              // f = 0 (t-units)
    __syncthreads();

    const int jp = tid >> 2, sl = tid & 3;
    const int pl = tid >> 4, ch = tid & 15;
    const int pp = sub * 64 + pl;
    const float qx = pxP[(pp >> 4) * 20 + (pp & 15)];
    const float qy = pyP[(pp >> 4) * 20 + (pp & 15)];

    float tt[16];

    auto partial_store = [&](int k) {
      const float pxj = pxP[(jp >> 4) * 20 + (jp & 15)];
      const float pyj = pyP[(jp >> 4) * 20 + (jp & 15)];
      const float4* F4 = (const float4*)F_own;
      const float4* px4 = (const float4*)pxP;
      const float4* py4 = (const float4*)pyP;
      float m = -INFINITY;
      #pragma unroll
      for (int q4 = 0; q4 < 4; ++q4) {
        float4 sx = px4[(sub * 4 + sl) * 5 + q4];
        float4 sy = py4[(sub * 4 + sl) * 5 + q4];
        float4 Fv = F4[sl * 4 + q4];
        #pragma unroll
        for (int e = 0; e < 4; ++e) {
          float dx = F4E(sx, e) - pxj, dq = F4E(sy, e) - pyj;
          float v = fmaf(fmaf(dq, dq, dx * dx), -0.5f, F4E(Fv, e));
          tt[q4 * 4 + e] = v; m = fmaxf(m, v);
        }
      }
      m = fmaxf(m, __shfl_xor(m, 1, 64));
      m = fmaxf(m, __shfl_xor(m, 2, 64));
      const float mk = m * KCONV;
      float ss = 0.0f;
      #pragma unroll
      for (int i = 0; i < 16; ++i) ss += EXP2F(fmaf(tt[i], KCONV, -mk));
      ss += __shfl_xor(ss, 1, 64);
      ss += __shfl_xor(ss, 2, 64);
      if (sl == 0)
        stp(EX + (k & 1) * 1024 + sub * 256 + jp, m + LOG2F(ss) * INV_KC, (unsigned)k & TAGM);
    };

    auto merge = [&](int k) -> float {
      const unsigned tg = (unsigned)k & TAGM;
      const unsigned int* p = EX + (k & 1) * 1024 + sl * 256 + jp;
      unsigned u;
      for (;;) {
        u = ldp(p);
        if (__all(((u & TAGM) ^ tg) == 0)) break;
        __builtin_amdgcn_s_sleep(1);
      }
      float m = __uint_as_float(u & ~TAGM);
      float ss = 1.0f;
      #pragma unroll
      for (int o = 1; o < 4; o <<= 1) {
        float mo = __shfl_xor(m, o, 64), so = __shfl_xor(ss, o, 64);
        float mn = fmaxf(m, mo);
        ss = ss * EXP2F((m - mn) * KCONV) + so * EXP2F((mo - mn) * KCONV);
        m = mn;
      }
      float g = -(m + LOG2F(ss) * INV_KC);
      if (sl == 0) G_L[(jp >> 4) * 20 + (jp & 15)] = g + EPS_LBC;
      return g;
    };

    auto fhalf = [&](int k) {
      const float4* GL4 = (const float4*)G_L;
      const float4* px4 = (const float4*)pxP;
      const float4* py4 = (const float4*)pyP;
      float m = -INFINITY;
      #pragma unroll
      for (int k4 = 0; k4 < 4; ++k4) {
        float4 pxv = px4[ch * 5 + k4], pyv = py4[ch * 5 + k4], Gv = GL4[ch * 5 + k4];
        #pragma unroll
        for (int e = 0; e < 4; ++e) {
          float dx = F4E(pxv, e) - qx, dq = F4E(pyv, e) - qy;
          float v = fmaf(fmaf(dq, dq, dx * dx), -0.5f, F4E(Gv, e));
          tt[k4 * 4 + e] = v; m = fmaxf(m, v);
        }
      }
      #pragma unroll
      for (int o = 1; o < 16; o <<= 1) m = fmaxf(m, __shfl_xor(m, o, 64));
      const float mk = m * KCONV;
      float ss = 0.0f;
      #pragma unroll
      for (int i = 0; i < 16; ++i) ss += EXP2F(fmaf(tt[i], KCONV, -mk));
      #pragma unroll
      for (int o = 1; o < 16; o <<= 1) ss += __shfl_xor(ss, o, 64);
      if (ch == 0) {
        float f = -(m + LOG2F(ss) * INV_KC);
        F_own[pl] = f + EPS_LBC;
        if (k == NITER) acc += f * (1.0f / 256.0f);  // sum b * f^100
      }
    };

    partial_store(1);
    for (int k = 1; k <= NITER; ++k) {
      merge(k);
      __syncthreads();
      fhalf(k);
      __syncthreads();
      partial_store(k + 1);
    }
    {
      float g = merge(NITER + 1);
      if (sub == 0 && sl == 0) acc += g * (1.0f / 256.0f);
    }
  } else {
    // ============ ot_aa : one block, separable LSE + verified diagonal collapse ============
    const int img = bid - 160;
    const float* dens = dens_all + img * NSRC;
    const float d_np = dens[tid];
    const float a_np = d_np;
    const float epsla_np = (d_np > 0.0f) ? EPSQ * __logf(d_np) : NEG_BIG;
    float myF = epsla_np;
    FaL[tid] = myF;
    __syncthreads();

    const int w = tid >> 6, lane = tid & 63;
    const int q1 = tid & 31, r1 = tid >> 5;
    const int q2 = q1, r2 = r1;

    auto aa_half = [&]() -> float {
      float cp = fmaxf(myF, __shfl_xor(myF, 32, 64));
      if (lane < 32) PM[w * 33 + lane] = cp;
      __syncthreads();
      if (tid < 32) {
        float cm = -INFINITY;
        #pragma unroll
        for (int w2 = 0; w2 < 16; ++w2) cm = fmaxf(cm, PM[w2 * 33 + tid]);
        CM[tid] = cm;
      }
      __syncthreads();
      const float fmx = CM[q1];
      float Tv;
      if (__all(fmx - 32.0f <= myF - 0.25f)) {
        Tv = myF;
      } else {
        float tv[32]; float m = -INFINITY; float d = (float)(-r1);
        #pragma unroll
        for (int rr = 0; rr < 32; ++rr) {
          float v = fmaf(d * d, -32.0f, FaL[rr * 32 + q1]);
          tv[rr] = v; m = fmaxf(m, v); d += 1.0f;
        }
        const float mk = m * KCONV; float s = 0.0f;
        #pragma unroll
        for (int rr = 0; rr < 32; ++rr) s += EXP2F(fmaf(tv[rr], KCONV, -mk));
        Tv = m + LOG2F(s) * INV_KC;
      }
      TaL[q1 * 33 + r1] = Tv;
      __syncthreads();
      float tmx = Tv;
      #pragma unroll
      for (int o = 1; o < 32; o <<= 1) tmx = fmaxf(tmx, __shfl_xor(tmx, o, 64));
      float outv;
      if (__all(tmx - 32.0f <= Tv - 0.25f)) {
        outv = Tv;
      } else {
        float tv[32]; float m = -INFINITY; float d = (float)(-q2);
        #pragma unroll
        for (int qi = 0; qi < 32; ++qi) {
          float v = fmaf(d * d, -32.0f, TaL[qi * 33 + r2]);
          tv[qi] = v; m = fmaxf(m, v); d += 1.0f;
        }
        const float mk = m * KCONV; float s = 0.0f;
        #pragma unroll
        for (int qi = 0; qi < 32; ++qi) s += EXP2F(fmaf(tv[qi], KCONV, -mk));
        outv = m + LOG2F(s) * INV_KC;
      }
      __syncthreads();
      return -outv;
    };

    for (int it = 0;; ++it) {
      float gpot = aa_half();
      if (it == NITER) { acc += a_np * gpot; break; }
      myF = gpot + epsla_np; FaL[tid] = myF;
      __syncthreads();
      float fpot = aa_half();
      if (it == NITER - 1) acc += a_np * fpot;
      myF = fpot + epsla_np; FaL[tid] = myF;
      __syncthreads();
    }
  }

  // ---- block reduction + per-block partial ----
  {
    #pragma unroll
    for (int o = 32; o; o >>= 1) acc += __shfl_xor(acc, o, 64);
    __syncthreads();
    if ((tid & 63) == 0) red[tid >> 6] = acc;
    __syncthreads();
    if (tid == 0) {
      float tsum = 0.0f;
      #pragma unroll
      for (int k = 0; k < 16; ++k) tsum += red[k];
      partials[bid] = tsum;
    }
  }
}

__global__ void ot_finalize(const float* __restrict__ partials, float* __restrict__ out) {
  __shared__ float red2[3];
  const int tid = threadIdx.x;
  float v = 0.0f;
  if (tid < 168) v = ((tid < 128) ? 1.0f : -0.5f) * partials[tid];
  #pragma unroll
  for (int o = 32; o; o >>= 1) v += __shfl_xor(v, o, 64);
  if ((tid & 63) == 0) red2[tid >> 6] = v;
  __syncthreads();
  if (tid == 0) out[0] = red2[0] + red2[1] + red2[2];
}

extern "C" void kernel_launch(void* const* d_in, const int* in_sizes, int n_in,
                              void* d_out, int out_size, void* d_ws, size_t ws_size,
                              hipStream_t stream) {
  const float* dens = (const float*)d_in[0];   // (8,1,32,32) f32
  const float* pts  = (const float*)d_in[1];   // (8,256,2)   f32
  unsigned int* wsu = (unsigned int*)d_ws;
  ot_sinkhorn<<<dim3(168), dim3(1024), 0, stream>>>(dens, pts, wsu);
  ot_finalize<<<dim3(1), dim3(192), 0, stream>>>((const float*)(wsu + WS_PART_W), (float*)d_out);
}